// Round 1
// baseline (376.096 us; speedup 1.0000x reference)
//
#include <hip/hip_runtime.h>
#include <math.h>

#define N 8192
#define D 256
#define TILE 128
#define BK 32
#define NT (N / TILE)                  // 64 tiles per dim
#define NTILES (NT * (NT + 1) / 2)     // 2080 triangular tiles
#define LSTR (TILE + 4)                // 132 floats: 16B-aligned rows, bank-spread

// ws layout: [0] double sum_a | [1] double sum_b | offset 16: float sq[N]

__global__ __launch_bounds__(256) void row_sq_kernel(const float* __restrict__ z,
                                                     float* __restrict__ sq,
                                                     double* __restrict__ sum_b) {
    const int lane = threadIdx.x & 63;
    const int wave = threadIdx.x >> 6;
    const int row = blockIdx.x * 4 + wave;
    float4 v = ((const float4*)(z + (size_t)row * D))[lane];
    float s = v.x * v.x + v.y * v.y + v.z * v.z + v.w * v.w;
    #pragma unroll
    for (int off = 32; off > 0; off >>= 1) s += __shfl_xor(s, off, 64);
    if (lane == 0) {
        sq[row] = s;
        atomicAdd(sum_b, (double)__expf(-0.25f * s));  // gamma/denom_b = 0.25
    }
}

__global__ __launch_bounds__(256) void pair_tile_kernel(const float* __restrict__ z,
                                                        const float* __restrict__ sq,
                                                        double* __restrict__ sum_a) {
    __shared__ __align__(16) float As[BK][LSTR];
    __shared__ __align__(16) float Bs[BK][LSTR];

    // decode linear block id -> triangular tile (bi, bj), bj >= bi
    int bi = 0, rem = blockIdx.x;
    while (rem >= NT - bi) { rem -= NT - bi; ++bi; }
    const int bj = bi + rem;
    const int i0 = bi * TILE, j0 = bj * TILE;

    const int t  = threadIdx.x;
    const int tx = t & 15, ty = t >> 4;
    const int lr = t >> 3;               // staging row 0..31 (+32m)
    const int lc = (t & 7) << 2;         // staging k-col 0,4,...,28

    float acc[8][8];
    #pragma unroll
    for (int a = 0; a < 8; ++a)
        #pragma unroll
        for (int b = 0; b < 8; ++b) acc[a][b] = 0.f;

    for (int kc = 0; kc < D; kc += BK) {
        __syncthreads();   // previous iter's LDS reads done before overwrite
        #pragma unroll
        for (int m = 0; m < 4; ++m) {
            const int row = lr + (m << 5);
            float4 va = *(const float4*)(z + (size_t)(i0 + row) * D + kc + lc);
            float4 vb = *(const float4*)(z + (size_t)(j0 + row) * D + kc + lc);
            As[lc + 0][row] = va.x; As[lc + 1][row] = va.y;
            As[lc + 2][row] = va.z; As[lc + 3][row] = va.w;
            Bs[lc + 0][row] = vb.x; Bs[lc + 1][row] = vb.y;
            Bs[lc + 2][row] = vb.z; Bs[lc + 3][row] = vb.w;
        }
        __syncthreads();
        #pragma unroll
        for (int k = 0; k < BK; ++k) {
            float4 alo = *(const float4*)&As[k][tx << 2];
            float4 ahi = *(const float4*)&As[k][64 + (tx << 2)];
            float4 blo = *(const float4*)&Bs[k][ty << 2];
            float4 bhi = *(const float4*)&Bs[k][64 + (ty << 2)];
            float av[8] = {alo.x, alo.y, alo.z, alo.w, ahi.x, ahi.y, ahi.z, ahi.w};
            float bv[8] = {blo.x, blo.y, blo.z, blo.w, bhi.x, bhi.y, bhi.z, bhi.w};
            #pragma unroll
            for (int a = 0; a < 8; ++a)
                #pragma unroll
                for (int b = 0; b < 8; ++b)
                    acc[a][b] = fmaf(av[a], bv[b], acc[a][b]);
        }
    }

    // epilogue: dist^2 = sq_i + sq_j - 2*dot, clamp, exp, sum
    float si[8], sj[8];
    #pragma unroll
    for (int a = 0; a < 4; ++a) {
        si[a]     = sq[i0 + (tx << 2) + a];
        si[a + 4] = sq[i0 + 64 + (tx << 2) + a];
        sj[a]     = sq[j0 + (ty << 2) + a];
        sj[a + 4] = sq[j0 + 64 + (ty << 2) + a];
    }
    float local = 0.f;
    #pragma unroll
    for (int a = 0; a < 8; ++a)
        #pragma unroll
        for (int b = 0; b < 8; ++b) {
            float dist = fmaxf(si[a] + sj[b] - 2.f * acc[a][b], 0.f);
            local += __expf(-0.5f * dist);   // gamma = 0.5
        }
    if (bi != bj) local *= 2.f;              // off-diagonal tiles count twice

    #pragma unroll
    for (int off = 32; off > 0; off >>= 1) local += __shfl_xor(local, off, 64);
    if ((t & 63) == 0) atomicAdd(sum_a, (double)local);
}

__global__ void final_kernel(const double* __restrict__ sums, float* __restrict__ out) {
    double term_a = sums[0] / ((double)N * (double)N);
    double mean_b = sums[1] / (double)N;
    double coeff_b = ldexp(1.0, -128);       // 1 / denom_b^(d/2) = 2^-128
    double term_c = 1.0;
    for (int i = 0; i < 128; ++i) term_c /= 3.0;   // (1+4*gamma)^-(d/2) = 3^-128
    out[0] = (float)(term_a - 2.0 * coeff_b * mean_b + term_c);
}

extern "C" void kernel_launch(void* const* d_in, const int* in_sizes, int n_in,
                              void* d_out, int out_size, void* d_ws, size_t ws_size,
                              hipStream_t stream) {
    const float* z = (const float*)d_in[0];
    double* sums = (double*)d_ws;
    float* sq = (float*)((char*)d_ws + 16);
    float* out = (float*)d_out;

    hipMemsetAsync(d_ws, 0, 16, stream);
    hipLaunchKernelGGL(row_sq_kernel, dim3(N / 4), dim3(256), 0, stream, z, sq, sums + 1);
    hipLaunchKernelGGL(pair_tile_kernel, dim3(NTILES), dim3(256), 0, stream, z, sq, sums + 0);
    hipLaunchKernelGGL(final_kernel, dim3(1), dim3(1), 0, stream, sums, out);
}

// Round 2
// 117.304 us; speedup vs baseline: 3.2062x; 3.2062x over previous
//
#include <hip/hip_runtime.h>
#include <math.h>

#define N 8192
#define D 256
#define TILE 128
#define NT (N / TILE)                  // 64 tiles per dim
#define NTILES (NT * (NT + 1) / 2)     // 2080 triangular tiles
#define BK 64
#define LSTR 72                        // LDS row stride in bf16 (64 + 8 pad; 144 B = 9*16B)

typedef float f32x4 __attribute__((ext_vector_type(4)));
typedef short s16x8 __attribute__((ext_vector_type(8)));

// ws layout:
//   offset 0       : float partials[NTILES]        (8320 B)
//   offset 16384   : float sq[N]                   (32768 B)
//   offset 65536   : ushort zb[N*D]  (bf16 bits)   (4 MiB)
#define WS_SQ_OFF 16384
#define WS_ZB_OFF 65536

__device__ __forceinline__ ushort f32_to_bf16_rne(float x) {
    unsigned u = __float_as_uint(x);
    return (ushort)((u + 0x7FFFu + ((u >> 16) & 1u)) >> 16);
}

__global__ __launch_bounds__(256) void prep_kernel(const float* __restrict__ z,
                                                   ushort* __restrict__ zb,
                                                   float* __restrict__ sq) {
    const int lane = threadIdx.x & 63;
    const int wave = threadIdx.x >> 6;
    const int row = blockIdx.x * 4 + wave;
    float4 v = ((const float4*)(z + (size_t)row * D))[lane];
    ushort4 b;
    b.x = f32_to_bf16_rne(v.x);
    b.y = f32_to_bf16_rne(v.y);
    b.z = f32_to_bf16_rne(v.z);
    b.w = f32_to_bf16_rne(v.w);
    ((ushort4*)(zb + (size_t)row * D))[lane] = b;
    float s = v.x * v.x + v.y * v.y + v.z * v.z + v.w * v.w;
    #pragma unroll
    for (int off = 32; off > 0; off >>= 1) s += __shfl_xor(s, off, 64);
    if (lane == 0) sq[row] = s;
}

__global__ __launch_bounds__(256) void pair_mfma_kernel(const ushort* __restrict__ zb,
                                                        const float* __restrict__ sq,
                                                        float* __restrict__ partials) {
    __shared__ __align__(16) ushort As[TILE][LSTR];
    __shared__ __align__(16) ushort Bs[TILE][LSTR];
    __shared__ float red[4];

    // decode linear block id -> triangular tile (bi, bj), bj >= bi
    int bi = 0, rem = blockIdx.x;
    while (rem >= NT - bi) { rem -= NT - bi; ++bi; }
    const int bj = bi + rem;
    const int i0 = bi * TILE, j0 = bj * TILE;

    const int t = threadIdx.x;
    const int lane = t & 63, wave = t >> 6;
    const int wi = wave >> 1, wj = wave & 1;     // 2x2 wave grid, 64x64 per wave
    const int col = lane & 15, q = lane >> 4;

    // staging: 2 threads per row, 64 B each
    const int sr = t >> 1;
    const int sh = t & 1;

    f32x4 acc[4][4];
    #pragma unroll
    for (int mt = 0; mt < 4; ++mt)
        #pragma unroll
        for (int nt = 0; nt < 4; ++nt)
            acc[mt][nt] = (f32x4){0.f, 0.f, 0.f, 0.f};

    for (int kc = 0; kc < D; kc += BK) {
        __syncthreads();
        {
            const s16x8* srcA = (const s16x8*)(zb + (size_t)(i0 + sr) * D + kc + sh * 32);
            const s16x8* srcB = (const s16x8*)(zb + (size_t)(j0 + sr) * D + kc + sh * 32);
            s16x8* dstA = (s16x8*)&As[sr][sh * 32];
            s16x8* dstB = (s16x8*)&Bs[sr][sh * 32];
            #pragma unroll
            for (int m = 0; m < 4; ++m) { dstA[m] = srcA[m]; dstB[m] = srcB[m]; }
        }
        __syncthreads();
        #pragma unroll
        for (int ks = 0; ks < 2; ++ks) {
            s16x8 af[4], bf[4];
            #pragma unroll
            for (int mt = 0; mt < 4; ++mt)
                af[mt] = *(const s16x8*)&As[wi * 64 + mt * 16 + col][ks * 32 + q * 8];
            #pragma unroll
            for (int nt = 0; nt < 4; ++nt)
                bf[nt] = *(const s16x8*)&Bs[wj * 64 + nt * 16 + col][ks * 32 + q * 8];
            #pragma unroll
            for (int mt = 0; mt < 4; ++mt)
                #pragma unroll
                for (int nt = 0; nt < 4; ++nt)
                    acc[mt][nt] = __builtin_amdgcn_mfma_f32_16x16x32_bf16(
                        af[mt], bf[nt], acc[mt][nt], 0, 0, 0);
        }
    }

    // epilogue: dist^2 = sq_i + sq_j - 2*dot; diagonal elements are exactly 1.0
    float sqj[4];
    #pragma unroll
    for (int nt = 0; nt < 4; ++nt) sqj[nt] = sq[j0 + wj * 64 + nt * 16 + col];

    float local = 0.f;
    #pragma unroll
    for (int mt = 0; mt < 4; ++mt) {
        const int li_base = wi * 64 + mt * 16 + q * 4;   // local row in 128-tile
        #pragma unroll
        for (int r = 0; r < 4; ++r) {
            const float sqi = sq[i0 + li_base + r];
            #pragma unroll
            for (int nt = 0; nt < 4; ++nt) {
                const int lj = wj * 64 + nt * 16 + col;  // local col in 128-tile
                float d = fmaxf(sqi + sqj[nt] - 2.f * acc[mt][nt][r], 0.f);
                float e = __expf(-0.5f * d);
                bool isdiag = (bi == bj) && (li_base + r == lj);
                local += isdiag ? 1.0f : e;
            }
        }
    }
    if (bi != bj) local *= 2.f;

    #pragma unroll
    for (int off = 32; off > 0; off >>= 1) local += __shfl_xor(local, off, 64);
    if (lane == 0) red[wave] = local;
    __syncthreads();
    if (t == 0) partials[blockIdx.x] = red[0] + red[1] + red[2] + red[3];
}

__global__ __launch_bounds__(256) void final_kernel(const float* __restrict__ partials,
                                                    const float* __restrict__ sq,
                                                    float* __restrict__ out) {
    __shared__ double redA[4], redB[4];
    const int t = threadIdx.x;
    double sa = 0.0, sb = 0.0;
    for (int i = t; i < NTILES; i += 256) sa += (double)partials[i];
    for (int i = t; i < N; i += 256) sb += exp(-0.25 * (double)sq[i]);
    #pragma unroll
    for (int off = 32; off > 0; off >>= 1) {
        sa += __shfl_xor(sa, off, 64);
        sb += __shfl_xor(sb, off, 64);
    }
    if ((t & 63) == 0) { redA[t >> 6] = sa; redB[t >> 6] = sb; }
    __syncthreads();
    if (t == 0) {
        double A = redA[0] + redA[1] + redA[2] + redA[3];
        double B = redB[0] + redB[1] + redB[2] + redB[3];
        double term_a = A / ((double)N * (double)N);
        double coeff_b = ldexp(1.0, -128);               // 1/2^128
        double term_c = 1.0;
        for (int i = 0; i < 128; ++i) term_c /= 3.0;     // 3^-128
        out[0] = (float)(term_a - 2.0 * coeff_b * (B / (double)N) + term_c);
    }
}

extern "C" void kernel_launch(void* const* d_in, const int* in_sizes, int n_in,
                              void* d_out, int out_size, void* d_ws, size_t ws_size,
                              hipStream_t stream) {
    const float* z = (const float*)d_in[0];
    float* partials = (float*)d_ws;
    float* sq = (float*)((char*)d_ws + WS_SQ_OFF);
    ushort* zb = (ushort*)((char*)d_ws + WS_ZB_OFF);
    float* out = (float*)d_out;

    hipLaunchKernelGGL(prep_kernel, dim3(N / 4), dim3(256), 0, stream, z, zb, sq);
    hipLaunchKernelGGL(pair_mfma_kernel, dim3(NTILES), dim3(256), 0, stream, zb, sq, partials);
    hipLaunchKernelGGL(final_kernel, dim3(1), dim3(256), 0, stream, partials, sq, out);
}

// Round 3
// 100.008 us; speedup vs baseline: 3.7607x; 1.1729x over previous
//
#include <hip/hip_runtime.h>
#include <math.h>

#define N 8192
#define D 256
#define TILE 128
#define NT (N / TILE)                  // 64 tiles per dim
#define NTILES (NT * (NT + 1) / 2)     // 2080 triangular tiles
#define BK 32
#define LSTR 40                        // LDS row stride in bf16 shorts (80 B, 16B-aligned)
#define NPREP (N / 4)                  // 2048 prep blocks
#define LOG2E 1.4426950408889634f

typedef float f32x4 __attribute__((ext_vector_type(4)));
typedef short s16x8 __attribute__((ext_vector_type(8)));

// ws layout:
//   offset 0       : float partialsA[NTILES]       (8320 B)
//   offset 12288   : float partialsB[NPREP]        (8192 B)
//   offset 32768   : float sq[N]                   (32768 B)
//   offset 65536   : ushort zb[N*D]  (bf16 bits)   (4 MiB)
#define WS_PB_OFF 12288
#define WS_SQ_OFF 32768
#define WS_ZB_OFF 65536

__device__ __forceinline__ ushort f32_to_bf16_rne(float x) {
    unsigned u = __float_as_uint(x);
    return (ushort)((u + 0x7FFFu + ((u >> 16) & 1u)) >> 16);
}

__global__ __launch_bounds__(256) void prep_kernel(const float* __restrict__ z,
                                                   ushort* __restrict__ zb,
                                                   float* __restrict__ sq,
                                                   float* __restrict__ partialsB) {
    __shared__ float pb4[4];
    const int t = threadIdx.x;
    const int lane = t & 63;
    const int wave = t >> 6;
    const int row = blockIdx.x * 4 + wave;
    float4 v = ((const float4*)(z + (size_t)row * D))[lane];
    ushort4 b;
    b.x = f32_to_bf16_rne(v.x);
    b.y = f32_to_bf16_rne(v.y);
    b.z = f32_to_bf16_rne(v.z);
    b.w = f32_to_bf16_rne(v.w);
    ((ushort4*)(zb + (size_t)row * D))[lane] = b;
    float s = v.x * v.x + v.y * v.y + v.z * v.z + v.w * v.w;
    #pragma unroll
    for (int off = 32; off > 0; off >>= 1) s += __shfl_xor(s, off, 64);
    if (lane == 0) {
        sq[row] = s;
        pb4[wave] = __expf(-0.25f * s);    // gamma/denom_b = 0.25 (term_b element)
    }
    __syncthreads();
    if (t == 0) partialsB[blockIdx.x] = pb4[0] + pb4[1] + pb4[2] + pb4[3];
}

__global__ __launch_bounds__(256) void pair_mfma_kernel(const ushort* __restrict__ zb,
                                                        const float* __restrict__ sq,
                                                        float* __restrict__ partialsA) {
    __shared__ __align__(16) ushort As[TILE][LSTR];
    __shared__ __align__(16) ushort Bs[TILE][LSTR];
    __shared__ float red[4];

    // decode linear block id -> triangular tile (bi, bj), bj >= bi
    int bi = 0, rem = blockIdx.x;
    while (rem >= NT - bi) { rem -= NT - bi; ++bi; }
    const int bj = bi + rem;
    const int i0 = bi * TILE, j0 = bj * TILE;

    const int t = threadIdx.x;
    const int lane = t & 63, wave = t >> 6;
    const int wi = wave >> 1, wj = wave & 1;     // 2x2 wave grid, 64x64 per wave
    const int col = lane & 15, q = lane >> 4;

    // staging: 2 threads per row, 32 B (16 shorts) each per K-chunk
    const int sr = t >> 1;
    const int sh = t & 1;
    const ushort* gA = zb + (size_t)(i0 + sr) * D + sh * 16;
    const ushort* gB = zb + (size_t)(j0 + sr) * D + sh * 16;

    // prefetch K-chunk 0 into registers
    s16x8 pa0 = *(const s16x8*)(gA);
    s16x8 pa1 = *(const s16x8*)(gA + 8);
    s16x8 pb0 = *(const s16x8*)(gB);
    s16x8 pb1 = *(const s16x8*)(gB + 8);

    f32x4 acc[4][4];
    #pragma unroll
    for (int mt = 0; mt < 4; ++mt)
        #pragma unroll
        for (int nt = 0; nt < 4; ++nt)
            acc[mt][nt] = (f32x4){0.f, 0.f, 0.f, 0.f};

    for (int kc = 0; kc < D; kc += BK) {
        __syncthreads();   // previous iter's LDS reads done before overwrite
        *(s16x8*)&As[sr][sh * 16]     = pa0;
        *(s16x8*)&As[sr][sh * 16 + 8] = pa1;
        *(s16x8*)&Bs[sr][sh * 16]     = pb0;
        *(s16x8*)&Bs[sr][sh * 16 + 8] = pb1;
        __syncthreads();
        if (kc + BK < D) {   // prefetch next chunk; waited on at next ds_write
            pa0 = *(const s16x8*)(gA + kc + BK);
            pa1 = *(const s16x8*)(gA + kc + BK + 8);
            pb0 = *(const s16x8*)(gB + kc + BK);
            pb1 = *(const s16x8*)(gB + kc + BK + 8);
        }
        s16x8 af[4], bf[4];
        #pragma unroll
        for (int mt = 0; mt < 4; ++mt)
            af[mt] = *(const s16x8*)&As[wi * 64 + mt * 16 + col][q * 8];
        #pragma unroll
        for (int nt = 0; nt < 4; ++nt)
            bf[nt] = *(const s16x8*)&Bs[wj * 64 + nt * 16 + col][q * 8];
        #pragma unroll
        for (int mt = 0; mt < 4; ++mt)
            #pragma unroll
            for (int nt = 0; nt < 4; ++nt)
                acc[mt][nt] = __builtin_amdgcn_mfma_f32_16x16x32_bf16(
                    af[mt], bf[nt], acc[mt][nt], 0, 0, 0);
    }

    // epilogue: exp(-0.5*dist^2) = exp2(acc*log2e + ci + cj), ci = -0.5*log2e*sq_i
    float cj[4];
    #pragma unroll
    for (int nt = 0; nt < 4; ++nt)
        cj[nt] = -0.5f * LOG2E * sq[j0 + wj * 64 + nt * 16 + col];

    float local = 0.f;
    if (bi != bj) {
        // off-diagonal tile: dist^2 >> 0 for this data, no clamp needed (both underflow)
        #pragma unroll
        for (int mt = 0; mt < 4; ++mt)
            #pragma unroll
            for (int r = 0; r < 4; ++r) {
                const float ci = -0.5f * LOG2E * sq[i0 + wi * 64 + mt * 16 + q * 4 + r];
                #pragma unroll
                for (int nt = 0; nt < 4; ++nt)
                    local += exp2f(fmaf(acc[mt][nt][r], LOG2E, ci) + cj[nt]);
            }
        local *= 2.f;   // counts for both triangles
    } else {
        // diagonal tile: clamp and force exact 1.0 on the true diagonal
        #pragma unroll
        for (int mt = 0; mt < 4; ++mt)
            #pragma unroll
            for (int r = 0; r < 4; ++r) {
                const int li = wi * 64 + mt * 16 + q * 4 + r;
                const float ci = -0.5f * LOG2E * sq[i0 + li];
                #pragma unroll
                for (int nt = 0; nt < 4; ++nt) {
                    const int lj = wj * 64 + nt * 16 + col;
                    float arg = fminf(fmaf(acc[mt][nt][r], LOG2E, ci) + cj[nt], 0.f);
                    local += (li == lj) ? 1.0f : exp2f(arg);
                }
            }
    }

    #pragma unroll
    for (int off = 32; off > 0; off >>= 1) local += __shfl_xor(local, off, 64);
    if (lane == 0) red[wave] = local;
    __syncthreads();
    if (t == 0) partialsA[blockIdx.x] = red[0] + red[1] + red[2] + red[3];
}

__global__ __launch_bounds__(256) void final_kernel(const float* __restrict__ partialsA,
                                                    const float* __restrict__ partialsB,
                                                    float* __restrict__ out) {
    __shared__ double redA[4], redB[4];
    const int t = threadIdx.x;
    double sa = 0.0, sb = 0.0;
    for (int i = t; i < NTILES; i += 256) sa += (double)partialsA[i];
    for (int i = t; i < NPREP; i += 256) sb += (double)partialsB[i];
    #pragma unroll
    for (int off = 32; off > 0; off >>= 1) {
        sa += __shfl_xor(sa, off, 64);
        sb += __shfl_xor(sb, off, 64);
    }
    if ((t & 63) == 0) { redA[t >> 6] = sa; redB[t >> 6] = sb; }
    __syncthreads();
    if (t == 0) {
        double A = redA[0] + redA[1] + redA[2] + redA[3];
        double B = redB[0] + redB[1] + redB[2] + redB[3];
        double term_a = A / ((double)N * (double)N);
        double coeff_b = ldexp(1.0, -128);               // 1/2^128
        double term_c = 1.0;
        for (int i = 0; i < 128; ++i) term_c /= 3.0;     // 3^-128
        out[0] = (float)(term_a - 2.0 * coeff_b * (B / (double)N) + term_c);
    }
}

extern "C" void kernel_launch(void* const* d_in, const int* in_sizes, int n_in,
                              void* d_out, int out_size, void* d_ws, size_t ws_size,
                              hipStream_t stream) {
    const float* z = (const float*)d_in[0];
    float* partialsA = (float*)d_ws;
    float* partialsB = (float*)((char*)d_ws + WS_PB_OFF);
    float* sq = (float*)((char*)d_ws + WS_SQ_OFF);
    ushort* zb = (ushort*)((char*)d_ws + WS_ZB_OFF);
    float* out = (float*)d_out;

    hipLaunchKernelGGL(prep_kernel, dim3(NPREP), dim3(256), 0, stream, z, zb, sq, partialsB);
    hipLaunchKernelGGL(pair_mfma_kernel, dim3(NTILES), dim3(256), 0, stream, zb, sq, partialsA);
    hipLaunchKernelGGL(final_kernel, dim3(1), dim3(256), 0, stream, partialsA, partialsB, out);
}